// Round 6
// baseline (372.462 us; speedup 1.0000x reference)
//
#include <hip/hip_runtime.h>
#include <math.h>

#define BB 4
#define NN 4096
#define DD 128
#define KK 8
#define NBLK 12

typedef __attribute__((ext_vector_type(8))) short short8;
typedef __attribute__((ext_vector_type(4))) float f32x4;

__device__ inline ushort bf16_rn(float x) {
    uint u = __float_as_uint(x);
    u = (u + 0x7FFFu + ((u >> 16) & 1u)) >> 16;
    return (ushort)u;
}
__device__ inline float bf16_f(ushort h) { return __uint_as_float(((uint)h) << 16); }

// ---------------- kNN (unchanged from R3: passes, 112us) ----------------
__global__ __launch_bounds__(512) void knn_kernel(const float* __restrict__ xyz,
                                                  int* __restrict__ idx) {
    __shared__ float xs[NN], ys[NN], zs[NN], sq[NN];
    const int b = blockIdx.y;
    const float* xb = xyz + (size_t)b * 3 * NN;
    for (int i = threadIdx.x; i < NN; i += 512) {
        float x = xb[i], y = xb[NN + i], z = xb[2 * NN + i];
        xs[i] = x; ys[i] = y; zs[i] = z;
        sq[i] = __fadd_rn(__fadd_rn(__fmul_rn(x, x), __fmul_rn(y, y)),
                          __fmul_rn(z, z));
    }
    __syncthreads();

    const int wave = threadIdx.x >> 6;
    const int lane = threadIdx.x & 63;
    const int n = blockIdx.x * 8 + wave;
    const float qx = xs[n], qy = ys[n], qz = zs[n], qsq = sq[n];

    float d[KK];
    int id[KK];
#pragma unroll
    for (int j = 0; j < KK; ++j) { d[j] = INFINITY; id[j] = -1; }

    for (int j = 0; j < NN / 256; ++j) {
        const int m0 = j * 256 + lane * 4;
        const float4 vx = *(const float4*)&xs[m0];
        const float4 vy = *(const float4*)&ys[m0];
        const float4 vz = *(const float4*)&zs[m0];
        const float4 vq = *(const float4*)&sq[m0];
#pragma unroll
        for (int e = 0; e < 4; ++e) {
            const float cx = (&vx.x)[e], cy = (&vy.x)[e], cz = (&vz.x)[e];
            const float cq = (&vq.x)[e];
            float inner = __fadd_rn(__fadd_rn(__fmul_rn(qx, cx),
                                              __fmul_rn(qy, cy)),
                                    __fmul_rn(qz, cz));
            float dist = __fadd_rn(__fsub_rn(qsq, __fmul_rn(2.0f, inner)), cq);
            if (dist < d[KK - 1]) {
                d[KK - 1] = dist; id[KK - 1] = m0 + e;
#pragma unroll
                for (int t = KK - 1; t > 0; --t) {
                    if (d[t] < d[t - 1]) {
                        float td = d[t]; d[t] = d[t - 1]; d[t - 1] = td;
                        int ti = id[t]; id[t] = id[t - 1]; id[t - 1] = ti;
                    }
                }
            }
        }
    }

    int out[KK];
#pragma unroll
    for (int it = 0; it < KK; ++it) {
        float hd = d[0];
        int hi = id[0];
#pragma unroll
        for (int s = 32; s; s >>= 1) {
            float od = __shfl_xor(hd, s, 64);
            int oi = __shfl_xor(hi, s, 64);
            if (od < hd || (od == hd && oi < hi)) { hd = od; hi = oi; }
        }
        out[it] = hi;
        if (hd == d[0] && hi == id[0]) {
#pragma unroll
            for (int t = 0; t < KK - 1; ++t) { d[t] = d[t + 1]; id[t] = id[t + 1]; }
            d[KK - 1] = INFINITY; id[KK - 1] = -1;
        }
    }

    if (lane == 0) {
        int* op = idx + ((size_t)b * NN + n) * KK;
        *(int4*)op       = make_int4(out[0], out[1], out[2], out[3]);
        *(int4*)(op + 4) = make_int4(out[4], out[5], out[6], out[7]);
    }
}

// ---------------- weight prep: Wcat = [W1 | W2] split to bf16 hi/lo -------
__global__ __launch_bounds__(256) void prep_w(const float* __restrict__ w1,
                                              const float* __restrict__ w2,
                                              ushort* __restrict__ whi,
                                              ushort* __restrict__ wlo) {
    const int e = blockIdx.x * 256 + threadIdx.x;     // l*32768 + r*256 + k
    const int l = e >> 15;
    const int rem = e & 32767;
    const int r = rem >> 8;
    const int k = rem & 255;
    float w = (k < 128) ? w1[((size_t)l * 128 + r) * 128 + k]
                        : w2[((size_t)l * 128 + r) * 128 + (k - 128)];
    ushort h = bf16_rn(w);
    whi[e] = h;
    wlo[e] = bf16_rn(w - bf16_f(h));
}

// ---------------- initial transpose: ptsT[b][n][c] = points[b][c][n] ------
__global__ __launch_bounds__(256) void transpose_pts(const float* __restrict__ pts,
                                                     float* __restrict__ ptsT) {
    __shared__ float t[32][33];
    const int b = blockIdx.z;
    const int c0 = blockIdx.y * 32;
    const int n0 = blockIdx.x * 32;
    const int tx = threadIdx.x & 31;
    const int ty = threadIdx.x >> 5;
#pragma unroll
    for (int q = 0; q < 4; ++q)
        t[ty + 8 * q][tx] = pts[((size_t)b * DD + c0 + ty + 8 * q) * NN + n0 + tx];
    __syncthreads();
#pragma unroll
    for (int q = 0; q < 4; ++q)
        ptsT[((size_t)b * NN + n0 + ty + 8 * q) * DD + c0 + tx] = t[tx][ty + 8 * q];
}

// ---------------- fused: relu+gather -> split bf16 -> MFMA -> residual ----
// block: 64 cols x 128 rows, 256 threads (4 waves).
// LDS: XT_hi[64][256] bf16 + XT_lo[64][256] bf16, granule-XOR swizzled:
//   elem (n,k) at byte n*512 + (((k>>3) ^ (n&7))<<4) + (k&7)*2
__global__ __launch_bounds__(256) void fused_block(const float* __restrict__ ptsT_in,
                                                   const int* __restrict__ idx,
                                                   const ushort* __restrict__ whi,
                                                   const ushort* __restrict__ wlo,
                                                   float* __restrict__ ptsT_out,
                                                   float* __restrict__ out_std,
                                                   float* __restrict__ PT,
                                                   float* __restrict__ GT,
                                                   const int last) {
    __shared__ __align__(16) char xt[65536];
    char* xt_hi = xt;
    char* xt_lo = xt + 32768;

    const int b = blockIdx.y;
    const int colbase = blockIdx.x * 64;
    const int w = threadIdx.x >> 6;
    const int lane = threadIdx.x & 63;

    const float* baseT = ptsT_in + (size_t)b * NN * DD;

    // ---- phase A: gather (coalesced 512B row reads), split, stage to LDS
    {
        // preload the wave's 16 idx rows: 128 ints -> int2 per lane
        const int* ibase = idx + ((size_t)b * NN + colbase + w * 16) * KK;
        int2 iv = *(const int2*)(ibase + lane * 2);

        for (int i = 0; i < 16; ++i) {
            const int n_loc = w * 16 + i;
            const int n = colbase + n_loc;
            int nb[KK];
#pragma unroll
            for (int j = 0; j < KK; ++j)
                nb[j] = __shfl((j & 1) ? iv.y : iv.x, i * 4 + (j >> 1), 64);

            const float2 c2 = *(const float2*)(baseT + (size_t)n * DD + 2 * lane);
            float gx = 0.0f, gy = 0.0f;
#pragma unroll
            for (int j = 0; j < KK; ++j) {
                const float2 u = *(const float2*)(baseT + (size_t)nb[j] * DD + 2 * lane);
                gx += fmaxf(u.x, 0.0f);
                gy += fmaxf(u.y, 0.0f);
            }
            const float px = fmaxf(c2.x, 0.0f);
            const float py = fmaxf(c2.y, 0.0f);

            // split to bf16 hi/lo
            ushort phx = bf16_rn(px), phy = bf16_rn(py);
            ushort plx = bf16_rn(px - bf16_f(phx)), ply = bf16_rn(py - bf16_f(phy));
            ushort ghx = bf16_rn(gx), ghy = bf16_rn(gy);
            ushort glx = bf16_rn(gx - bf16_f(ghx)), gly = bf16_rn(gy - bf16_f(ghy));

            const int kP = 2 * lane;
            const int kG = 128 + 2 * lane;
            const int byP = n_loc * 512 + ((((kP >> 3) ^ (n_loc & 7))) << 4) + ((kP & 7) << 1);
            const int byG = n_loc * 512 + ((((kG >> 3) ^ (n_loc & 7))) << 4) + ((kG & 7) << 1);
            *(uint*)(xt_hi + byP) = (uint)phx | ((uint)phy << 16);
            *(uint*)(xt_lo + byP) = (uint)plx | ((uint)ply << 16);
            *(uint*)(xt_hi + byG) = (uint)ghx | ((uint)ghy << 16);
            *(uint*)(xt_lo + byG) = (uint)glx | ((uint)gly << 16);

            if (last) {   // dump P,G (fp32, [n][c] layout) for the head kernel
                *(float2*)(PT + ((size_t)b * NN + n) * DD + 2 * lane) = make_float2(px, py);
                *(float2*)(GT + ((size_t)b * NN + n) * DD + 2 * lane) = make_float2(gx, gy);
            }
        }
    }
    __syncthreads();

    // ---- phase B: MFMA. wave w: rows w*32..w*32+31 (2 rowtiles), 4 ntiles
    const int ln15 = lane & 15;
    const int kl = lane >> 4;

    f32x4 acc[2][4] = {};
#pragma unroll
    for (int pass = 0; pass < 3; ++pass) {
        const ushort* Wp = (pass == 2) ? wlo : whi;
        const char* Xp = (pass == 1) ? xt_lo : xt_hi;
#pragma unroll
        for (int ks = 0; ks < 8; ++ks) {
            short8 a[2];
#pragma unroll
            for (int rt = 0; rt < 2; ++rt) {
                const int row = w * 32 + rt * 16 + ln15;
                a[rt] = *(const short8*)(Wp + (size_t)row * 256 + ks * 32 + kl * 8);
            }
            short8 bf[4];
#pragma unroll
            for (int nt = 0; nt < 4; ++nt) {
                const int n_loc = nt * 16 + ln15;
                const int by = n_loc * 512 + (((ks * 4 + kl) ^ (n_loc & 7)) << 4);
                bf[nt] = *(const short8*)(Xp + by);
            }
#pragma unroll
            for (int rt = 0; rt < 2; ++rt)
#pragma unroll
                for (int nt = 0; nt < 4; ++nt)
                    acc[rt][nt] = __builtin_amdgcn_mfma_f32_16x16x32_bf16(
                        a[rt], bf[nt], acc[rt][nt], 0, 0, 0);
        }
    }

    // ---- phase C: epilogue: out = acc/9 + shortcut
    const float inv = 1.0f / 9.0f;
#pragma unroll
    for (int rt = 0; rt < 2; ++rt) {
#pragma unroll
        for (int nt = 0; nt < 4; ++nt) {
            const int row = w * 32 + rt * 16 + (lane >> 4) * 4;
            const int n = colbase + nt * 16 + ln15;
            const float4 sc = *(const float4*)(baseT + (size_t)n * DD + row);
            float v0 = acc[rt][nt][0] * inv + sc.x;
            float v1 = acc[rt][nt][1] * inv + sc.y;
            float v2 = acc[rt][nt][2] * inv + sc.z;
            float v3 = acc[rt][nt][3] * inv + sc.w;
            if (!last) {
                *(float4*)(ptsT_out + ((size_t)b * NN + n) * DD + row) =
                    make_float4(v0, v1, v2, v3);
            } else {     // final points -> d_out in standard [b][c][n] layout
                out_std[((size_t)b * DD + row + 0) * NN + n] = v0;
                out_std[((size_t)b * DD + row + 1) * NN + n] = v1;
                out_std[((size_t)b * DD + row + 2) * NN + n] = v2;
                out_std[((size_t)b * DD + row + 3) * NN + n] = v3;
            }
        }
    }
}

// ---------------- final unpool head (reads PT/GT in [n][c] layout) --------
__global__ __launch_bounds__(256) void final_head(const float* __restrict__ PT,
                                                  const float* __restrict__ GT,
                                                  const float* __restrict__ wc,
                                                  const float* __restrict__ wn,
                                                  const float* __restrict__ xyz,
                                                  float* __restrict__ out) {
    __shared__ float wcs[6][128], wns[6][128];
    const int b = blockIdx.y;
    for (int i = threadIdx.x; i < 6 * 128; i += 256) {
        wcs[i >> 7][i & 127] = wc[i];
        wns[i >> 7][i & 127] = wn[i];
    }
    __syncthreads();

    const int w = threadIdx.x >> 6;
    const int lane = threadIdx.x & 63;
    const float inv = 1.0f / 9.0f;

    for (int i = 0; i < 16; ++i) {
        const int n = blockIdx.x * 64 + w * 16 + i;
        const float2 p2 = *(const float2*)(PT + ((size_t)b * NN + n) * DD + 2 * lane);
        const float2 g2 = *(const float2*)(GT + ((size_t)b * NN + n) * DD + 2 * lane);
        float s[6];
#pragma unroll
        for (int o = 0; o < 6; ++o) {
            s[o] = p2.x * wcs[o][2 * lane] + p2.y * wcs[o][2 * lane + 1]
                 + g2.x * wns[o][2 * lane] + g2.y * wns[o][2 * lane + 1];
        }
#pragma unroll
        for (int st = 32; st; st >>= 1) {
#pragma unroll
            for (int o = 0; o < 6; ++o) s[o] += __shfl_xor(s[o], st, 64);
        }
        if (lane < 6) {
            const int dd = lane >> 1, h = lane & 1;
            const float xv = xyz[((size_t)b * 3 + dd) * NN + n];
            out[(((size_t)b * 3 + dd) * 2 + h) * NN + n] = s[lane] * inv + xv;
        }
    }
}

extern "C" void kernel_launch(void* const* d_in, const int* in_sizes, int n_in,
                              void* d_out, int out_size, void* d_ws, size_t ws_size,
                              hipStream_t stream) {
    const float* xyz    = (const float*)d_in[0];
    const float* points = (const float*)d_in[1];
    const float* w1     = (const float*)d_in[2];
    const float* w2     = (const float*)d_in[3];
    const float* wc     = (const float*)d_in[4];
    const float* wn     = (const float*)d_in[5];
    float* out = (float*)d_out;

    const size_t feat = (size_t)BB * DD * NN;          // 2,097,152 floats
    char* ws = (char*)d_ws;
    int*    idx  = (int*)ws;                            // 512 KB
    ushort* whi  = (ushort*)(ws + 524288);              // 768 KB
    ushort* wlo  = (ushort*)(ws + 524288 + 786432);     // 768 KB
    float*  pT0  = (float*)(ws + 524288 + 2 * 786432);  // 8 MB
    float*  pT1  = pT0 + feat;                          // 8 MB
    float*  PT   = pT1 + feat;                          // 8 MB
    float*  GT   = PT + feat;                           // 8 MB

    knn_kernel<<<dim3(NN / 8, BB), 512, 0, stream>>>(xyz, idx);
    prep_w<<<dim3(12 * 128 * 256 / 256), 256, 0, stream>>>(w1, w2, whi, wlo);
    transpose_pts<<<dim3(NN / 32, DD / 32, BB), 256, 0, stream>>>(points, pT0);

    float* out_pts = out + (size_t)BB * 3 * 2 * NN;
    float* bufs[2] = {pT0, pT1};
    for (int i = 0; i < NBLK; ++i) {
        const int last = (i == NBLK - 1);
        fused_block<<<dim3(NN / 64, BB), 256, 0, stream>>>(
            bufs[i & 1], idx, whi + (size_t)i * 32768, wlo + (size_t)i * 32768,
            bufs[(i + 1) & 1], out_pts, PT, GT, last);
    }

    final_head<<<dim3(NN / 64, BB), 256, 0, stream>>>(PT, GT, wc, wn, xyz, out);
}

// Round 7
// 371.696 us; speedup vs baseline: 1.0021x; 1.0021x over previous
//
#include <hip/hip_runtime.h>
#include <math.h>

#define BB 4
#define NN 4096
#define DD 128
#define KK 8
#define NBLK 12

typedef __attribute__((ext_vector_type(8))) short short8;
typedef __attribute__((ext_vector_type(4))) float f32x4;

__device__ inline ushort bf16_rn(float x) {
    uint u = __float_as_uint(x);
    u = (u + 0x7FFFu + ((u >> 16) & 1u)) >> 16;
    return (ushort)u;
}
__device__ inline float bf16_f(ushort h) { return __uint_as_float(((uint)h) << 16); }

// ---------------- kNN (unchanged from R3: passes, 112us) ----------------
__global__ __launch_bounds__(512) void knn_kernel(const float* __restrict__ xyz,
                                                  int* __restrict__ idx) {
    __shared__ float xs[NN], ys[NN], zs[NN], sq[NN];
    const int b = blockIdx.y;
    const float* xb = xyz + (size_t)b * 3 * NN;
    for (int i = threadIdx.x; i < NN; i += 512) {
        float x = xb[i], y = xb[NN + i], z = xb[2 * NN + i];
        xs[i] = x; ys[i] = y; zs[i] = z;
        sq[i] = __fadd_rn(__fadd_rn(__fmul_rn(x, x), __fmul_rn(y, y)),
                          __fmul_rn(z, z));
    }
    __syncthreads();

    const int wave = threadIdx.x >> 6;
    const int lane = threadIdx.x & 63;
    const int n = blockIdx.x * 8 + wave;
    const float qx = xs[n], qy = ys[n], qz = zs[n], qsq = sq[n];

    float d[KK];
    int id[KK];
#pragma unroll
    for (int j = 0; j < KK; ++j) { d[j] = INFINITY; id[j] = -1; }

    for (int j = 0; j < NN / 256; ++j) {
        const int m0 = j * 256 + lane * 4;
        const float4 vx = *(const float4*)&xs[m0];
        const float4 vy = *(const float4*)&ys[m0];
        const float4 vz = *(const float4*)&zs[m0];
        const float4 vq = *(const float4*)&sq[m0];
#pragma unroll
        for (int e = 0; e < 4; ++e) {
            const float cx = (&vx.x)[e], cy = (&vy.x)[e], cz = (&vz.x)[e];
            const float cq = (&vq.x)[e];
            float inner = __fadd_rn(__fadd_rn(__fmul_rn(qx, cx),
                                              __fmul_rn(qy, cy)),
                                    __fmul_rn(qz, cz));
            float dist = __fadd_rn(__fsub_rn(qsq, __fmul_rn(2.0f, inner)), cq);
            if (dist < d[KK - 1]) {
                d[KK - 1] = dist; id[KK - 1] = m0 + e;
#pragma unroll
                for (int t = KK - 1; t > 0; --t) {
                    if (d[t] < d[t - 1]) {
                        float td = d[t]; d[t] = d[t - 1]; d[t - 1] = td;
                        int ti = id[t]; id[t] = id[t - 1]; id[t - 1] = ti;
                    }
                }
            }
        }
    }

    int out[KK];
#pragma unroll
    for (int it = 0; it < KK; ++it) {
        float hd = d[0];
        int hi = id[0];
#pragma unroll
        for (int s = 32; s; s >>= 1) {
            float od = __shfl_xor(hd, s, 64);
            int oi = __shfl_xor(hi, s, 64);
            if (od < hd || (od == hd && oi < hi)) { hd = od; hi = oi; }
        }
        out[it] = hi;
        if (hd == d[0] && hi == id[0]) {
#pragma unroll
            for (int t = 0; t < KK - 1; ++t) { d[t] = d[t + 1]; id[t] = id[t + 1]; }
            d[KK - 1] = INFINITY; id[KK - 1] = -1;
        }
    }

    if (lane == 0) {
        int* op = idx + ((size_t)b * NN + n) * KK;
        *(int4*)op       = make_int4(out[0], out[1], out[2], out[3]);
        *(int4*)(op + 4) = make_int4(out[4], out[5], out[6], out[7]);
    }
}

// ---------------- weight prep: Wcat = [W1 | W2] split to bf16 hi/lo -------
__global__ __launch_bounds__(256) void prep_w(const float* __restrict__ w1,
                                              const float* __restrict__ w2,
                                              ushort* __restrict__ whi,
                                              ushort* __restrict__ wlo) {
    const int e = blockIdx.x * 256 + threadIdx.x;     // l*32768 + r*256 + k
    const int l = e >> 15;
    const int rem = e & 32767;
    const int r = rem >> 8;
    const int k = rem & 255;
    float w = (k < 128) ? w1[((size_t)l * 128 + r) * 128 + k]
                        : w2[((size_t)l * 128 + r) * 128 + (k - 128)];
    ushort h = bf16_rn(w);
    whi[e] = h;
    wlo[e] = bf16_rn(w - bf16_f(h));
}

// ---------------- initial transpose: ptsT[b][n][c] = points[b][c][n] ------
__global__ __launch_bounds__(256) void transpose_pts(const float* __restrict__ pts,
                                                     float* __restrict__ ptsT) {
    __shared__ float t[32][33];
    const int b = blockIdx.z;
    const int c0 = blockIdx.y * 32;
    const int n0 = blockIdx.x * 32;
    const int tx = threadIdx.x & 31;
    const int ty = threadIdx.x >> 5;
#pragma unroll
    for (int q = 0; q < 4; ++q)
        t[ty + 8 * q][tx] = pts[((size_t)b * DD + c0 + ty + 8 * q) * NN + n0 + tx];
    __syncthreads();
#pragma unroll
    for (int q = 0; q < 4; ++q)
        ptsT[((size_t)b * NN + n0 + ty + 8 * q) * DD + c0 + tx] = t[tx][ty + 8 * q];
}

// ---------------- fused: relu+gather -> split bf16 -> MFMA -> residual ----
// block: 64 cols x 128 rows, 256 threads (4 waves).
// LDS: XT_hi[64][256] bf16 + XT_lo[64][256] bf16, granule-XOR swizzled:
//   elem (n,k) at byte n*512 + (((k>>3) ^ (n&7))<<4) + (k&7)*2
__global__ __launch_bounds__(256) void fused_block(const float* __restrict__ ptsT_in,
                                                   const int* __restrict__ idx,
                                                   const ushort* __restrict__ whi,
                                                   const ushort* __restrict__ wlo,
                                                   float* __restrict__ ptsT_out,
                                                   float* __restrict__ out_std,
                                                   float* __restrict__ PT,
                                                   float* __restrict__ GT,
                                                   const int last) {
    __shared__ __align__(16) char xt[65536];
    char* xt_hi = xt;
    char* xt_lo = xt + 32768;

    const int b = blockIdx.y;
    const int colbase = blockIdx.x * 64;
    const int w = threadIdx.x >> 6;
    const int lane = threadIdx.x & 63;

    const float* baseT = ptsT_in + (size_t)b * NN * DD;

    // ---- phase A: gather (coalesced 512B row reads), split, stage to LDS
    {
        // preload the wave's 16 idx rows: 128 ints -> int2 per lane
        const int* ibase = idx + ((size_t)b * NN + colbase + w * 16) * KK;
        int2 iv = *(const int2*)(ibase + lane * 2);

        for (int i = 0; i < 16; ++i) {
            const int n_loc = w * 16 + i;
            const int n = colbase + n_loc;
            int nb[KK];
#pragma unroll
            for (int j = 0; j < KK; ++j)
                nb[j] = __shfl((j & 1) ? iv.y : iv.x, i * 4 + (j >> 1), 64);

            const float2 c2 = *(const float2*)(baseT + (size_t)n * DD + 2 * lane);
            float gx = 0.0f, gy = 0.0f;
#pragma unroll
            for (int j = 0; j < KK; ++j) {
                const float2 u = *(const float2*)(baseT + (size_t)nb[j] * DD + 2 * lane);
                gx += fmaxf(u.x, 0.0f);
                gy += fmaxf(u.y, 0.0f);
            }
            const float px = fmaxf(c2.x, 0.0f);
            const float py = fmaxf(c2.y, 0.0f);

            // split to bf16 hi/lo
            ushort phx = bf16_rn(px), phy = bf16_rn(py);
            ushort plx = bf16_rn(px - bf16_f(phx)), ply = bf16_rn(py - bf16_f(phy));
            ushort ghx = bf16_rn(gx), ghy = bf16_rn(gy);
            ushort glx = bf16_rn(gx - bf16_f(ghx)), gly = bf16_rn(gy - bf16_f(ghy));

            const int kP = 2 * lane;
            const int kG = 128 + 2 * lane;
            const int byP = n_loc * 512 + ((((kP >> 3) ^ (n_loc & 7))) << 4) + ((kP & 7) << 1);
            const int byG = n_loc * 512 + ((((kG >> 3) ^ (n_loc & 7))) << 4) + ((kG & 7) << 1);
            *(uint*)(xt_hi + byP) = (uint)phx | ((uint)phy << 16);
            *(uint*)(xt_lo + byP) = (uint)plx | ((uint)ply << 16);
            *(uint*)(xt_hi + byG) = (uint)ghx | ((uint)ghy << 16);
            *(uint*)(xt_lo + byG) = (uint)glx | ((uint)gly << 16);

            if (last) {   // dump P,G (fp32, [n][c] layout) for the head kernel
                *(float2*)(PT + ((size_t)b * NN + n) * DD + 2 * lane) = make_float2(px, py);
                *(float2*)(GT + ((size_t)b * NN + n) * DD + 2 * lane) = make_float2(gx, gy);
            }
        }
    }
    __syncthreads();

    // ---- phase B: MFMA. wave w: rows w*32..w*32+31 (2 rowtiles), 4 ntiles
    const int ln15 = lane & 15;
    const int kl = lane >> 4;

    f32x4 acc[2][4] = {};
#pragma unroll
    for (int pass = 0; pass < 3; ++pass) {
        const ushort* Wp = (pass == 2) ? wlo : whi;
        const char* Xp = (pass == 1) ? xt_lo : xt_hi;
#pragma unroll
        for (int ks = 0; ks < 8; ++ks) {
            short8 a[2];
#pragma unroll
            for (int rt = 0; rt < 2; ++rt) {
                const int row = w * 32 + rt * 16 + ln15;
                a[rt] = *(const short8*)(Wp + (size_t)row * 256 + ks * 32 + kl * 8);
            }
            short8 bf[4];
#pragma unroll
            for (int nt = 0; nt < 4; ++nt) {
                const int n_loc = nt * 16 + ln15;
                const int by = n_loc * 512 + (((ks * 4 + kl) ^ (n_loc & 7)) << 4);
                bf[nt] = *(const short8*)(Xp + by);
            }
#pragma unroll
            for (int rt = 0; rt < 2; ++rt)
#pragma unroll
                for (int nt = 0; nt < 4; ++nt)
                    acc[rt][nt] = __builtin_amdgcn_mfma_f32_16x16x32_bf16(
                        a[rt], bf[nt], acc[rt][nt], 0, 0, 0);
        }
    }

    // ---- phase C: epilogue: out = acc/9 + shortcut
    const float inv = 1.0f / 9.0f;
#pragma unroll
    for (int rt = 0; rt < 2; ++rt) {
#pragma unroll
        for (int nt = 0; nt < 4; ++nt) {
            const int row = w * 32 + rt * 16 + (lane >> 4) * 4;
            const int n = colbase + nt * 16 + ln15;
            const float4 sc = *(const float4*)(baseT + (size_t)n * DD + row);
            float v0 = acc[rt][nt][0] * inv + sc.x;
            float v1 = acc[rt][nt][1] * inv + sc.y;
            float v2 = acc[rt][nt][2] * inv + sc.z;
            float v3 = acc[rt][nt][3] * inv + sc.w;
            if (!last) {
                *(float4*)(ptsT_out + ((size_t)b * NN + n) * DD + row) =
                    make_float4(v0, v1, v2, v3);
            } else {     // final points -> d_out in standard [b][c][n] layout
                out_std[((size_t)b * DD + row + 0) * NN + n] = v0;
                out_std[((size_t)b * DD + row + 1) * NN + n] = v1;
                out_std[((size_t)b * DD + row + 2) * NN + n] = v2;
                out_std[((size_t)b * DD + row + 3) * NN + n] = v3;
            }
        }
    }
}

// ---------------- final unpool head (reads PT/GT in [n][c] layout) --------
__global__ __launch_bounds__(256) void final_head(const float* __restrict__ PT,
                                                  const float* __restrict__ GT,
                                                  const float* __restrict__ wc,
                                                  const float* __restrict__ wn,
                                                  const float* __restrict__ xyz,
                                                  float* __restrict__ out) {
    __shared__ float wcs[6][128], wns[6][128];
    const int b = blockIdx.y;
    for (int i = threadIdx.x; i < 6 * 128; i += 256) {
        wcs[i >> 7][i & 127] = wc[i];
        wns[i >> 7][i & 127] = wn[i];
    }
    __syncthreads();

    const int w = threadIdx.x >> 6;
    const int lane = threadIdx.x & 63;
    const float inv = 1.0f / 9.0f;

    for (int i = 0; i < 16; ++i) {
        const int n = blockIdx.x * 64 + w * 16 + i;
        const float2 p2 = *(const float2*)(PT + ((size_t)b * NN + n) * DD + 2 * lane);
        const float2 g2 = *(const float2*)(GT + ((size_t)b * NN + n) * DD + 2 * lane);
        float s[6];
#pragma unroll
        for (int o = 0; o < 6; ++o) {
            s[o] = p2.x * wcs[o][2 * lane] + p2.y * wcs[o][2 * lane + 1]
                 + g2.x * wns[o][2 * lane] + g2.y * wns[o][2 * lane + 1];
        }
#pragma unroll
        for (int st = 32; st; st >>= 1) {
#pragma unroll
            for (int o = 0; o < 6; ++o) s[o] += __shfl_xor(s[o], st, 64);
        }
        if (lane < 6) {
            const int dd = lane >> 1, h = lane & 1;
            const float xv = xyz[((size_t)b * 3 + dd) * NN + n];
            out[(((size_t)b * 3 + dd) * 2 + h) * NN + n] = s[lane] * inv + xv;
        }
    }
}

extern "C" void kernel_launch(void* const* d_in, const int* in_sizes, int n_in,
                              void* d_out, int out_size, void* d_ws, size_t ws_size,
                              hipStream_t stream) {
    const float* xyz    = (const float*)d_in[0];
    const float* points = (const float*)d_in[1];
    const float* w1     = (const float*)d_in[2];
    const float* w2     = (const float*)d_in[3];
    const float* wc     = (const float*)d_in[4];
    const float* wn     = (const float*)d_in[5];
    float* out = (float*)d_out;

    const size_t feat = (size_t)BB * DD * NN;          // 2,097,152 floats
    char* ws = (char*)d_ws;
    int*    idx  = (int*)ws;                            // 512 KB
    ushort* whi  = (ushort*)(ws + 524288);              // 768 KB
    ushort* wlo  = (ushort*)(ws + 524288 + 786432);     // 768 KB
    float*  pT0  = (float*)(ws + 524288 + 2 * 786432);  // 8 MB
    float*  pT1  = pT0 + feat;                          // 8 MB
    float*  PT   = pT1 + feat;                          // 8 MB
    float*  GT   = PT + feat;                           // 8 MB

    knn_kernel<<<dim3(NN / 8, BB), 512, 0, stream>>>(xyz, idx);
    prep_w<<<dim3(12 * 128 * 256 / 256), 256, 0, stream>>>(w1, w2, whi, wlo);
    transpose_pts<<<dim3(NN / 32, DD / 32, BB), 256, 0, stream>>>(points, pT0);

    float* out_pts = out + (size_t)BB * 3 * 2 * NN;
    float* bufs[2] = {pT0, pT1};
    for (int i = 0; i < NBLK; ++i) {
        const int last = (i == NBLK - 1);
        fused_block<<<dim3(NN / 64, BB), 256, 0, stream>>>(
            bufs[i & 1], idx, whi + (size_t)i * 32768, wlo + (size_t)i * 32768,
            bufs[(i + 1) & 1], out_pts, PT, GT, last);
    }

    final_head<<<dim3(NN / 64, BB), 256, 0, stream>>>(PT, GT, wc, wn, xyz, out);
}

// Round 8
// 338.723 us; speedup vs baseline: 1.0996x; 1.0973x over previous
//
#include <hip/hip_runtime.h>
#include <math.h>

#define BB 4
#define NN 4096
#define DD 128
#define KK 8
#define NBLK 12

typedef __attribute__((ext_vector_type(8))) short short8;
typedef __attribute__((ext_vector_type(4))) float f32x4;

__device__ inline ushort bf16_rn(float x) {
    uint u = __float_as_uint(x);
    u = (u + 0x7FFFu + ((u >> 16) & 1u)) >> 16;
    return (ushort)u;
}
__device__ inline float bf16_f(ushort h) { return __uint_as_float(((uint)h) << 16); }

// ---------------- kNN (unchanged: passes, ~112us) ----------------
__global__ __launch_bounds__(512) void knn_kernel(const float* __restrict__ xyz,
                                                  int* __restrict__ idx) {
    __shared__ float xs[NN], ys[NN], zs[NN], sq[NN];
    const int b = blockIdx.y;
    const float* xb = xyz + (size_t)b * 3 * NN;
    for (int i = threadIdx.x; i < NN; i += 512) {
        float x = xb[i], y = xb[NN + i], z = xb[2 * NN + i];
        xs[i] = x; ys[i] = y; zs[i] = z;
        sq[i] = __fadd_rn(__fadd_rn(__fmul_rn(x, x), __fmul_rn(y, y)),
                          __fmul_rn(z, z));
    }
    __syncthreads();

    const int wave = threadIdx.x >> 6;
    const int lane = threadIdx.x & 63;
    const int n = blockIdx.x * 8 + wave;
    const float qx = xs[n], qy = ys[n], qz = zs[n], qsq = sq[n];

    float d[KK];
    int id[KK];
#pragma unroll
    for (int j = 0; j < KK; ++j) { d[j] = INFINITY; id[j] = -1; }

    for (int j = 0; j < NN / 256; ++j) {
        const int m0 = j * 256 + lane * 4;
        const float4 vx = *(const float4*)&xs[m0];
        const float4 vy = *(const float4*)&ys[m0];
        const float4 vz = *(const float4*)&zs[m0];
        const float4 vq = *(const float4*)&sq[m0];
#pragma unroll
        for (int e = 0; e < 4; ++e) {
            const float cx = (&vx.x)[e], cy = (&vy.x)[e], cz = (&vz.x)[e];
            const float cq = (&vq.x)[e];
            float inner = __fadd_rn(__fadd_rn(__fmul_rn(qx, cx),
                                              __fmul_rn(qy, cy)),
                                    __fmul_rn(qz, cz));
            float dist = __fadd_rn(__fsub_rn(qsq, __fmul_rn(2.0f, inner)), cq);
            if (dist < d[KK - 1]) {
                d[KK - 1] = dist; id[KK - 1] = m0 + e;
#pragma unroll
                for (int t = KK - 1; t > 0; --t) {
                    if (d[t] < d[t - 1]) {
                        float td = d[t]; d[t] = d[t - 1]; d[t - 1] = td;
                        int ti = id[t]; id[t] = id[t - 1]; id[t - 1] = ti;
                    }
                }
            }
        }
    }

    int out[KK];
#pragma unroll
    for (int it = 0; it < KK; ++it) {
        float hd = d[0];
        int hi = id[0];
#pragma unroll
        for (int s = 32; s; s >>= 1) {
            float od = __shfl_xor(hd, s, 64);
            int oi = __shfl_xor(hi, s, 64);
            if (od < hd || (od == hd && oi < hi)) { hd = od; hi = oi; }
        }
        out[it] = hi;
        if (hd == d[0] && hi == id[0]) {
#pragma unroll
            for (int t = 0; t < KK - 1; ++t) { d[t] = d[t + 1]; id[t] = id[t + 1]; }
            d[KK - 1] = INFINITY; id[KK - 1] = -1;
        }
    }

    if (lane == 0) {
        int* op = idx + ((size_t)b * NN + n) * KK;
        *(int4*)op       = make_int4(out[0], out[1], out[2], out[3]);
        *(int4*)(op + 4) = make_int4(out[4], out[5], out[6], out[7]);
    }
}

// ---------------- weight prep: Wcat = [W1 | W2] split to bf16 hi/lo -------
__global__ __launch_bounds__(256) void prep_w(const float* __restrict__ w1,
                                              const float* __restrict__ w2,
                                              ushort* __restrict__ whi,
                                              ushort* __restrict__ wlo) {
    const int e = blockIdx.x * 256 + threadIdx.x;     // l*32768 + r*256 + k
    const int l = e >> 15;
    const int rem = e & 32767;
    const int r = rem >> 8;
    const int k = rem & 255;
    float w = (k < 128) ? w1[((size_t)l * 128 + r) * 128 + k]
                        : w2[((size_t)l * 128 + r) * 128 + (k - 128)];
    ushort h = bf16_rn(w);
    whi[e] = h;
    wlo[e] = bf16_rn(w - bf16_f(h));
}

// ---------------- initial transpose: ptsT[b][n][c] = points[b][c][n] ------
__global__ __launch_bounds__(256) void transpose_pts(const float* __restrict__ pts,
                                                     float* __restrict__ ptsT) {
    __shared__ float t[32][33];
    const int b = blockIdx.z;
    const int c0 = blockIdx.y * 32;
    const int n0 = blockIdx.x * 32;
    const int tx = threadIdx.x & 31;
    const int ty = threadIdx.x >> 5;
#pragma unroll
    for (int q = 0; q < 4; ++q)
        t[ty + 8 * q][tx] = pts[((size_t)b * DD + c0 + ty + 8 * q) * NN + n0 + tx];
    __syncthreads();
#pragma unroll
    for (int q = 0; q < 4; ++q)
        ptsT[((size_t)b * NN + n0 + ty + 8 * q) * DD + c0 + tx] = t[tx][ty + 8 * q];
}

// ---------------- fused: gather -> split bf16 -> MFMA -> residual ---------
// 32 cols x 128 rows per block, 256 threads (4 waves), grid 512 (2/CU).
// XCD-aware decode: batch b pinned to 2 XCDs for gather L2 locality.
// LDS: X hi/lo bf16 swizzled (16KB+16KB) + fp32 shortcut sc[32][132] (16.5KB).
__global__ __launch_bounds__(256) void fused_block(const float* __restrict__ ptsT_in,
                                                   const int* __restrict__ idx,
                                                   const ushort* __restrict__ whi,
                                                   const ushort* __restrict__ wlo,
                                                   float* __restrict__ ptsT_out,
                                                   float* __restrict__ out_std,
                                                   const float* __restrict__ wc,
                                                   const float* __restrict__ wn,
                                                   const float* __restrict__ xyz,
                                                   float* __restrict__ out_xyz,
                                                   const int last) {
    __shared__ __align__(16) char xt[32768];
    __shared__ float sc[32][132];
    char* xt_hi = xt;
    char* xt_lo = xt + 16384;

    const int bid = blockIdx.x;
    const int xcd = bid & 7;
    const int b = xcd >> 1;                         // 2 XCDs per batch
    const int colbase = (((xcd & 1) << 6) + (bid >> 3)) * 32;

    const int w = threadIdx.x >> 6;
    const int lane = threadIdx.x & 63;

    const float* baseT = ptsT_in + (size_t)b * NN * DD;

    // ---- phase A: gather (coalesced 512B row reads), split, stage to LDS
    {
        const int row0 = w * 8;                     // wave owns rows row0..row0+7
        const int iv = idx[((size_t)b * NN + colbase + row0) * KK + lane];

        for (int i = 0; i < 8; ++i) {
            const int n_loc = row0 + i;
            const int n = colbase + n_loc;
            int nb[KK];
#pragma unroll
            for (int j = 0; j < KK; ++j) nb[j] = __shfl(iv, i * 8 + j, 64);

            const float2 c2 = *(const float2*)(baseT + (size_t)n * DD + 2 * lane);
            float gx = 0.0f, gy = 0.0f;
#pragma unroll
            for (int j = 0; j < KK; ++j) {
                const float2 u = *(const float2*)(baseT + (size_t)nb[j] * DD + 2 * lane);
                gx += fmaxf(u.x, 0.0f);
                gy += fmaxf(u.y, 0.0f);
            }
            const float px = fmaxf(c2.x, 0.0f);
            const float py = fmaxf(c2.y, 0.0f);

            sc[n_loc][2 * lane]     = c2.x;         // shortcut cache (pre-relu)
            sc[n_loc][2 * lane + 1] = c2.y;

            ushort phx = bf16_rn(px), phy = bf16_rn(py);
            ushort plx = bf16_rn(px - bf16_f(phx)), ply = bf16_rn(py - bf16_f(phy));
            ushort ghx = bf16_rn(gx), ghy = bf16_rn(gy);
            ushort glx = bf16_rn(gx - bf16_f(ghx)), gly = bf16_rn(gy - bf16_f(ghy));

            const int kP = 2 * lane;
            const int kG = 128 + 2 * lane;
            const int byP = n_loc * 512 + ((((kP >> 3) ^ (n_loc & 7))) << 4) + ((kP & 7) << 1);
            const int byG = n_loc * 512 + ((((kG >> 3) ^ (n_loc & 7))) << 4) + ((kG & 7) << 1);
            *(uint*)(xt_hi + byP) = (uint)phx | ((uint)phy << 16);
            *(uint*)(xt_lo + byP) = (uint)plx | ((uint)ply << 16);
            *(uint*)(xt_hi + byG) = (uint)ghx | ((uint)ghy << 16);
            *(uint*)(xt_lo + byG) = (uint)glx | ((uint)gly << 16);

            if (last) {   // fused unpool head: s[o] = wc[o]·p + wn[o]·g, reduce
                float s0, s1, s2, s3, s4, s5;
                {
                    const int c0 = 2 * lane, c1 = 2 * lane + 1;
                    s0 = px * wc[0 * 128 + c0] + py * wc[0 * 128 + c1]
                       + gx * wn[0 * 128 + c0] + gy * wn[0 * 128 + c1];
                    s1 = px * wc[1 * 128 + c0] + py * wc[1 * 128 + c1]
                       + gx * wn[1 * 128 + c0] + gy * wn[1 * 128 + c1];
                    s2 = px * wc[2 * 128 + c0] + py * wc[2 * 128 + c1]
                       + gx * wn[2 * 128 + c0] + gy * wn[2 * 128 + c1];
                    s3 = px * wc[3 * 128 + c0] + py * wc[3 * 128 + c1]
                       + gx * wn[3 * 128 + c0] + gy * wn[3 * 128 + c1];
                    s4 = px * wc[4 * 128 + c0] + py * wc[4 * 128 + c1]
                       + gx * wn[4 * 128 + c0] + gy * wn[4 * 128 + c1];
                    s5 = px * wc[5 * 128 + c0] + py * wc[5 * 128 + c1]
                       + gx * wn[5 * 128 + c0] + gy * wn[5 * 128 + c1];
                }
#pragma unroll
                for (int st = 32; st; st >>= 1) {
                    s0 += __shfl_xor(s0, st, 64);
                    s1 += __shfl_xor(s1, st, 64);
                    s2 += __shfl_xor(s2, st, 64);
                    s3 += __shfl_xor(s3, st, 64);
                    s4 += __shfl_xor(s4, st, 64);
                    s5 += __shfl_xor(s5, st, 64);
                }
                if (lane < 6) {
                    float v = s0;
                    v = (lane == 1) ? s1 : v;
                    v = (lane == 2) ? s2 : v;
                    v = (lane == 3) ? s3 : v;
                    v = (lane == 4) ? s4 : v;
                    v = (lane == 5) ? s5 : v;
                    const int dd = lane >> 1, h = lane & 1;
                    const float xv = xyz[((size_t)b * 3 + dd) * NN + n];
                    out_xyz[(((size_t)b * 3 + dd) * 2 + h) * NN + n] =
                        v * (1.0f / 9.0f) + xv;
                }
            }
        }
    }
    __syncthreads();

    // ---- phase B: MFMA. wave w: rows w*32..w*32+31, 2 ntiles
    const int ln15 = lane & 15;
    const int kl = lane >> 4;

    f32x4 acc[2][2] = {};
#pragma unroll
    for (int pass = 0; pass < 3; ++pass) {
        const ushort* Wp = (pass == 2) ? wlo : whi;
        const char* Xp = (pass == 1) ? xt_lo : xt_hi;
#pragma unroll
        for (int ks = 0; ks < 8; ++ks) {
            short8 a[2];
#pragma unroll
            for (int rt = 0; rt < 2; ++rt) {
                const int row = w * 32 + rt * 16 + ln15;
                a[rt] = *(const short8*)(Wp + (size_t)row * 256 + ks * 32 + kl * 8);
            }
            short8 bf[2];
#pragma unroll
            for (int nt = 0; nt < 2; ++nt) {
                const int n_loc = nt * 16 + ln15;
                const int by = n_loc * 512 + (((ks * 4 + kl) ^ (n_loc & 7)) << 4);
                bf[nt] = *(const short8*)(Xp + by);
            }
#pragma unroll
            for (int rt = 0; rt < 2; ++rt)
#pragma unroll
                for (int nt = 0; nt < 2; ++nt)
                    acc[rt][nt] = __builtin_amdgcn_mfma_f32_16x16x32_bf16(
                        a[rt], bf[nt], acc[rt][nt], 0, 0, 0);
        }
    }

    // ---- phase C: epilogue: out = acc/9 + shortcut (from LDS)
    const float inv = 1.0f / 9.0f;
#pragma unroll
    for (int rt = 0; rt < 2; ++rt) {
#pragma unroll
        for (int nt = 0; nt < 2; ++nt) {
            const int row = w * 32 + rt * 16 + (lane >> 4) * 4;
            const int nl = nt * 16 + ln15;
            const int n = colbase + nl;
            const float4 scv = *(const float4*)&sc[nl][row];
            float v0 = acc[rt][nt][0] * inv + scv.x;
            float v1 = acc[rt][nt][1] * inv + scv.y;
            float v2 = acc[rt][nt][2] * inv + scv.z;
            float v3 = acc[rt][nt][3] * inv + scv.w;
            if (!last) {
                *(float4*)(ptsT_out + ((size_t)b * NN + n) * DD + row) =
                    make_float4(v0, v1, v2, v3);
            } else {
                out_std[((size_t)b * DD + row + 0) * NN + n] = v0;
                out_std[((size_t)b * DD + row + 1) * NN + n] = v1;
                out_std[((size_t)b * DD + row + 2) * NN + n] = v2;
                out_std[((size_t)b * DD + row + 3) * NN + n] = v3;
            }
        }
    }
}

extern "C" void kernel_launch(void* const* d_in, const int* in_sizes, int n_in,
                              void* d_out, int out_size, void* d_ws, size_t ws_size,
                              hipStream_t stream) {
    const float* xyz    = (const float*)d_in[0];
    const float* points = (const float*)d_in[1];
    const float* w1     = (const float*)d_in[2];
    const float* w2     = (const float*)d_in[3];
    const float* wc     = (const float*)d_in[4];
    const float* wn     = (const float*)d_in[5];
    float* out = (float*)d_out;

    const size_t feat = (size_t)BB * DD * NN;          // 2,097,152 floats
    char* ws = (char*)d_ws;
    int*    idx  = (int*)ws;                            // 512 KB
    ushort* whi  = (ushort*)(ws + 524288);              // 768 KB
    ushort* wlo  = (ushort*)(ws + 524288 + 786432);     // 768 KB
    float*  pT0  = (float*)(ws + 524288 + 2 * 786432);  // 8 MB
    float*  pT1  = pT0 + feat;                          // 8 MB

    knn_kernel<<<dim3(NN / 8, BB), 512, 0, stream>>>(xyz, idx);
    prep_w<<<dim3(12 * 128 * 256 / 256), 256, 0, stream>>>(w1, w2, whi, wlo);
    transpose_pts<<<dim3(NN / 32, DD / 32, BB), 256, 0, stream>>>(points, pT0);

    float* out_pts = out + (size_t)BB * 3 * 2 * NN;
    float* bufs[2] = {pT0, pT1};
    for (int i = 0; i < NBLK; ++i) {
        const int last = (i == NBLK - 1);
        fused_block<<<dim3(512), 256, 0, stream>>>(
            bufs[i & 1], idx, whi + (size_t)i * 32768, wlo + (size_t)i * 32768,
            bufs[(i + 1) & 1], out_pts, wc, wn, xyz, out, last);
    }
}

// Round 9
// 332.319 us; speedup vs baseline: 1.1208x; 1.0193x over previous
//
#include <hip/hip_runtime.h>
#include <math.h>

#define BB 4
#define NN 4096
#define DD 128
#define KK 8
#define NBLK 12

typedef __attribute__((ext_vector_type(8))) short short8;
typedef __attribute__((ext_vector_type(4))) float f32x4;

__device__ inline ushort bf16_rn(float x) {
    uint u = __float_as_uint(x);
    u = (u + 0x7FFFu + ((u >> 16) & 1u)) >> 16;
    return (ushort)u;
}
__device__ inline float bf16_f(ushort h) { return __uint_as_float(((uint)h) << 16); }

// ---------------- kNN: wave-per-query + wave-threshold pruned selection ----
// dist emulates reference f32: (sq[n] - 2*inner) + sq[m], RN, no FMA.
// Prune: thr = wave-min of per-lane 8th-smallest. thr >= global 8th, so
// skipping dist > thr never drops a true top-8 member; a lane skipping a
// candidate >= its own d[7] is dominated by 8 better same-lane entries.
__global__ __launch_bounds__(512) void knn_kernel(const float* __restrict__ xyz,
                                                  int* __restrict__ idx) {
    __shared__ float xs[NN], ys[NN], zs[NN], sq[NN];
    const int b = blockIdx.y;
    const float* xb = xyz + (size_t)b * 3 * NN;
    for (int i = threadIdx.x; i < NN; i += 512) {
        float x = xb[i], y = xb[NN + i], z = xb[2 * NN + i];
        xs[i] = x; ys[i] = y; zs[i] = z;
        sq[i] = __fadd_rn(__fadd_rn(__fmul_rn(x, x), __fmul_rn(y, y)),
                          __fmul_rn(z, z));
    }
    __syncthreads();

    const int wave = threadIdx.x >> 6;
    const int lane = threadIdx.x & 63;
    const int n = blockIdx.x * 8 + wave;
    const float qx = xs[n], qy = ys[n], qz = zs[n], qsq = sq[n];

    float d[KK];
    int id[KK];
#pragma unroll
    for (int j = 0; j < KK; ++j) { d[j] = INFINITY; id[j] = -1; }

    float thr = INFINITY;

    for (int j = 0; j < NN / 256; ++j) {
        const int m0 = j * 256 + lane * 4;
        const float4 vx = *(const float4*)&xs[m0];
        const float4 vy = *(const float4*)&ys[m0];
        const float4 vz = *(const float4*)&zs[m0];
        const float4 vq = *(const float4*)&sq[m0];
#pragma unroll
        for (int e = 0; e < 4; ++e) {
            const float cx = (&vx.x)[e], cy = (&vy.x)[e], cz = (&vz.x)[e];
            const float cq = (&vq.x)[e];
            float inner = __fadd_rn(__fadd_rn(__fmul_rn(qx, cx),
                                              __fmul_rn(qy, cy)),
                                    __fmul_rn(qz, cz));
            float dist = __fadd_rn(__fsub_rn(qsq, __fmul_rn(2.0f, inner)), cq);
            const bool ins = (dist < d[KK - 1]) && (dist <= thr);
            if (__any(ins)) {                       // execz-skipped rare path
                if (ins) {
                    d[KK - 1] = dist; id[KK - 1] = m0 + e;
#pragma unroll
                    for (int t = KK - 1; t > 0; --t) {
                        if (d[t] < d[t - 1]) {
                            float td = d[t]; d[t] = d[t - 1]; d[t - 1] = td;
                            int ti = id[t]; id[t] = id[t - 1]; id[t - 1] = ti;
                        }
                    }
                }
            }
        }
        // refresh prune threshold (stale by <=1 chunk: conservative)
        float t = d[KK - 1];
#pragma unroll
        for (int s = 32; s; s >>= 1) t = fminf(t, __shfl_xor(t, s, 64));
        thr = t;
    }

    int out[KK];
#pragma unroll
    for (int it = 0; it < KK; ++it) {
        float hd = d[0];
        int hi = id[0];
#pragma unroll
        for (int s = 32; s; s >>= 1) {
            float od = __shfl_xor(hd, s, 64);
            int oi = __shfl_xor(hi, s, 64);
            if (od < hd || (od == hd && oi < hi)) { hd = od; hi = oi; }
        }
        out[it] = hi;
        if (hd == d[0] && hi == id[0]) {
#pragma unroll
            for (int t = 0; t < KK - 1; ++t) { d[t] = d[t + 1]; id[t] = id[t + 1]; }
            d[KK - 1] = INFINITY; id[KK - 1] = -1;
        }
    }

    if (lane == 0) {
        int* op = idx + ((size_t)b * NN + n) * KK;
        *(int4*)op       = make_int4(out[0], out[1], out[2], out[3]);
        *(int4*)(op + 4) = make_int4(out[4], out[5], out[6], out[7]);
    }
}

// ---------------- weight prep: Wcat = [W1 | W2] split to bf16 hi/lo -------
__global__ __launch_bounds__(256) void prep_w(const float* __restrict__ w1,
                                              const float* __restrict__ w2,
                                              ushort* __restrict__ whi,
                                              ushort* __restrict__ wlo) {
    const int e = blockIdx.x * 256 + threadIdx.x;     // l*32768 + r*256 + k
    const int l = e >> 15;
    const int rem = e & 32767;
    const int r = rem >> 8;
    const int k = rem & 255;
    float w = (k < 128) ? w1[((size_t)l * 128 + r) * 128 + k]
                        : w2[((size_t)l * 128 + r) * 128 + (k - 128)];
    ushort h = bf16_rn(w);
    whi[e] = h;
    wlo[e] = bf16_rn(w - bf16_f(h));
}

// ---------------- initial transpose: ptsT[b][n][c] = points[b][c][n] ------
__global__ __launch_bounds__(256) void transpose_pts(const float* __restrict__ pts,
                                                     float* __restrict__ ptsT) {
    __shared__ float t[32][33];
    const int b = blockIdx.z;
    const int c0 = blockIdx.y * 32;
    const int n0 = blockIdx.x * 32;
    const int tx = threadIdx.x & 31;
    const int ty = threadIdx.x >> 5;
#pragma unroll
    for (int q = 0; q < 4; ++q)
        t[ty + 8 * q][tx] = pts[((size_t)b * DD + c0 + ty + 8 * q) * NN + n0 + tx];
    __syncthreads();
#pragma unroll
    for (int q = 0; q < 4; ++q)
        ptsT[((size_t)b * NN + n0 + ty + 8 * q) * DD + c0 + tx] = t[tx][ty + 8 * q];
}

// ---------------- fused: gather -> split bf16 -> MFMA -> residual ---------
// 32 cols x 128 rows per block, 256 threads (4 waves), grid 512 (2/CU).
// Phase A is 2-deep software-pipelined: row i+1's loads issue before row i
// is consumed.
__global__ __launch_bounds__(256) void fused_block(const float* __restrict__ ptsT_in,
                                                   const int* __restrict__ idx,
                                                   const ushort* __restrict__ whi,
                                                   const ushort* __restrict__ wlo,
                                                   float* __restrict__ ptsT_out,
                                                   float* __restrict__ out_std,
                                                   const float* __restrict__ wc,
                                                   const float* __restrict__ wn,
                                                   const float* __restrict__ xyz,
                                                   float* __restrict__ out_xyz,
                                                   const int last) {
    __shared__ __align__(16) char xt[32768];
    __shared__ float sc[32][132];
    char* xt_hi = xt;
    char* xt_lo = xt + 16384;

    const int bid = blockIdx.x;
    const int xcd = bid & 7;
    const int b = xcd >> 1;                         // 2 XCDs per batch
    const int colbase = (((xcd & 1) << 6) + (bid >> 3)) * 32;

    const int w = threadIdx.x >> 6;
    const int lane = threadIdx.x & 63;

    const float* baseT = ptsT_in + (size_t)b * NN * DD;

    // ---- phase A: pipelined gather, split, stage to LDS
    {
        const int row0 = w * 8;
        const int iv = idx[((size_t)b * NN + colbase + row0) * KK + lane];

        float2 c2, u[KK];
        {
            int nb[KK];
#pragma unroll
            for (int j = 0; j < KK; ++j) nb[j] = __shfl(iv, j, 64);
            c2 = *(const float2*)(baseT + (size_t)(colbase + row0) * DD + 2 * lane);
#pragma unroll
            for (int j = 0; j < KK; ++j)
                u[j] = *(const float2*)(baseT + (size_t)nb[j] * DD + 2 * lane);
        }

#pragma unroll
        for (int i = 0; i < 8; ++i) {
            // issue next row's loads first (hide latency under consume)
            float2 c2n, un[KK];
            if (i < 7) {
                int nbn[KK];
#pragma unroll
                for (int j = 0; j < KK; ++j) nbn[j] = __shfl(iv, (i + 1) * 8 + j, 64);
                c2n = *(const float2*)(baseT + (size_t)(colbase + row0 + i + 1) * DD + 2 * lane);
#pragma unroll
                for (int j = 0; j < KK; ++j)
                    un[j] = *(const float2*)(baseT + (size_t)nbn[j] * DD + 2 * lane);
            }

            // consume current row
            const int n_loc = row0 + i;
            const int n = colbase + n_loc;
            float gx = 0.0f, gy = 0.0f;
#pragma unroll
            for (int j = 0; j < KK; ++j) {
                gx += fmaxf(u[j].x, 0.0f);
                gy += fmaxf(u[j].y, 0.0f);
            }
            const float px = fmaxf(c2.x, 0.0f);
            const float py = fmaxf(c2.y, 0.0f);

            sc[n_loc][2 * lane]     = c2.x;
            sc[n_loc][2 * lane + 1] = c2.y;

            ushort phx = bf16_rn(px), phy = bf16_rn(py);
            ushort plx = bf16_rn(px - bf16_f(phx)), ply = bf16_rn(py - bf16_f(phy));
            ushort ghx = bf16_rn(gx), ghy = bf16_rn(gy);
            ushort glx = bf16_rn(gx - bf16_f(ghx)), gly = bf16_rn(gy - bf16_f(ghy));

            const int kP = 2 * lane;
            const int kG = 128 + 2 * lane;
            const int byP = n_loc * 512 + ((((kP >> 3) ^ (n_loc & 7))) << 4) + ((kP & 7) << 1);
            const int byG = n_loc * 512 + ((((kG >> 3) ^ (n_loc & 7))) << 4) + ((kG & 7) << 1);
            *(uint*)(xt_hi + byP) = (uint)phx | ((uint)phy << 16);
            *(uint*)(xt_lo + byP) = (uint)plx | ((uint)ply << 16);
            *(uint*)(xt_hi + byG) = (uint)ghx | ((uint)ghy << 16);
            *(uint*)(xt_lo + byG) = (uint)glx | ((uint)gly << 16);

            if (last) {   // fused unpool head
                float s0, s1, s2, s3, s4, s5;
                {
                    const int c0 = 2 * lane, c1 = 2 * lane + 1;
                    s0 = px * wc[0 * 128 + c0] + py * wc[0 * 128 + c1]
                       + gx * wn[0 * 128 + c0] + gy * wn[0 * 128 + c1];
                    s1 = px * wc[1 * 128 + c0] + py * wc[1 * 128 + c1]
                       + gx * wn[1 * 128 + c0] + gy * wn[1 * 128 + c1];
                    s2 = px * wc[2 * 128 + c0] + py * wc[2 * 128 + c1]
                       + gx * wn[2 * 128 + c0] + gy * wn[2 * 128 + c1];
                    s3 = px * wc[3 * 128 + c0] + py * wc[3 * 128 + c1]
                       + gx * wn[3 * 128 + c0] + gy * wn[3 * 128 + c1];
                    s4 = px * wc[4 * 128 + c0] + py * wc[4 * 128 + c1]
                       + gx * wn[4 * 128 + c0] + gy * wn[4 * 128 + c1];
                    s5 = px * wc[5 * 128 + c0] + py * wc[5 * 128 + c1]
                       + gx * wn[5 * 128 + c0] + gy * wn[5 * 128 + c1];
                }
#pragma unroll
                for (int st = 32; st; st >>= 1) {
                    s0 += __shfl_xor(s0, st, 64);
                    s1 += __shfl_xor(s1, st, 64);
                    s2 += __shfl_xor(s2, st, 64);
                    s3 += __shfl_xor(s3, st, 64);
                    s4 += __shfl_xor(s4, st, 64);
                    s5 += __shfl_xor(s5, st, 64);
                }
                if (lane < 6) {
                    float v = s0;
                    v = (lane == 1) ? s1 : v;
                    v = (lane == 2) ? s2 : v;
                    v = (lane == 3) ? s3 : v;
                    v = (lane == 4) ? s4 : v;
                    v = (lane == 5) ? s5 : v;
                    const int dd = lane >> 1, h = lane & 1;
                    const float xv = xyz[((size_t)b * 3 + dd) * NN + n];
                    out_xyz[(((size_t)b * 3 + dd) * 2 + h) * NN + n] =
                        v * (1.0f / 9.0f) + xv;
                }
            }

            if (i < 7) {
                c2 = c2n;
#pragma unroll
                for (int j = 0; j < KK; ++j) u[j] = un[j];
            }
        }
    }
    __syncthreads();

    // ---- phase B: MFMA. wave w: rows w*32..w*32+31, 2 ntiles
    const int ln15 = lane & 15;
    const int kl = lane >> 4;

    f32x4 acc[2][2] = {};
#pragma unroll
    for (int pass = 0; pass < 3; ++pass) {
        const ushort* Wp = (pass == 2) ? wlo : whi;
        const char* Xp = (pass == 1) ? xt_lo : xt_hi;
#pragma unroll
        for (int ks = 0; ks < 8; ++ks) {
            short8 a[2];
#pragma unroll
            for (int rt = 0; rt < 2; ++rt) {
                const int row = w * 32 + rt * 16 + ln15;
                a[rt] = *(const short8*)(Wp + (size_t)row * 256 + ks * 32 + kl * 8);
            }
            short8 bf[2];
#pragma unroll
            for (int nt = 0; nt < 2; ++nt) {
                const int n_loc = nt * 16 + ln15;
                const int by = n_loc * 512 + (((ks * 4 + kl) ^ (n_loc & 7)) << 4);
                bf[nt] = *(const short8*)(Xp + by);
            }
#pragma unroll
            for (int rt = 0; rt < 2; ++rt)
#pragma unroll
                for (int nt = 0; nt < 2; ++nt)
                    acc[rt][nt] = __builtin_amdgcn_mfma_f32_16x16x32_bf16(
                        a[rt], bf[nt], acc[rt][nt], 0, 0, 0);
        }
    }

    // ---- phase C: epilogue: out = acc/9 + shortcut (from LDS)
    const float inv = 1.0f / 9.0f;
#pragma unroll
    for (int rt = 0; rt < 2; ++rt) {
#pragma unroll
        for (int nt = 0; nt < 2; ++nt) {
            const int row = w * 32 + rt * 16 + (lane >> 4) * 4;
            const int nl = nt * 16 + ln15;
            const int n = colbase + nl;
            const float4 scv = *(const float4*)&sc[nl][row];
            float v0 = acc[rt][nt][0] * inv + scv.x;
            float v1 = acc[rt][nt][1] * inv + scv.y;
            float v2 = acc[rt][nt][2] * inv + scv.z;
            float v3 = acc[rt][nt][3] * inv + scv.w;
            if (!last) {
                *(float4*)(ptsT_out + ((size_t)b * NN + n) * DD + row) =
                    make_float4(v0, v1, v2, v3);
            } else {
                out_std[((size_t)b * DD + row + 0) * NN + n] = v0;
                out_std[((size_t)b * DD + row + 1) * NN + n] = v1;
                out_std[((size_t)b * DD + row + 2) * NN + n] = v2;
                out_std[((size_t)b * DD + row + 3) * NN + n] = v3;
            }
        }
    }
}

extern "C" void kernel_launch(void* const* d_in, const int* in_sizes, int n_in,
                              void* d_out, int out_size, void* d_ws, size_t ws_size,
                              hipStream_t stream) {
    const float* xyz    = (const float*)d_in[0];
    const float* points = (const float*)d_in[1];
    const float* w1     = (const float*)d_in[2];
    const float* w2     = (const float*)d_in[3];
    const float* wc     = (const float*)d_in[4];
    const float* wn     = (const float*)d_in[5];
    float* out = (float*)d_out;

    const size_t feat = (size_t)BB * DD * NN;          // 2,097,152 floats
    char* ws = (char*)d_ws;
    int*    idx  = (int*)ws;                            // 512 KB
    ushort* whi  = (ushort*)(ws + 524288);              // 768 KB
    ushort* wlo  = (ushort*)(ws + 524288 + 786432);     // 768 KB
    float*  pT0  = (float*)(ws + 524288 + 2 * 786432);  // 8 MB
    float*  pT1  = pT0 + feat;                          // 8 MB

    knn_kernel<<<dim3(NN / 8, BB), 512, 0, stream>>>(xyz, idx);
    prep_w<<<dim3(12 * 128 * 256 / 256), 256, 0, stream>>>(w1, w2, whi, wlo);
    transpose_pts<<<dim3(NN / 32, DD / 32, BB), 256, 0, stream>>>(points, pT0);

    float* out_pts = out + (size_t)BB * 3 * 2 * NN;
    float* bufs[2] = {pT0, pT1};
    for (int i = 0; i < NBLK; ++i) {
        const int last = (i == NBLK - 1);
        fused_block<<<dim3(512), 256, 0, stream>>>(
            bufs[i & 1], idx, whi + (size_t)i * 32768, wlo + (size_t)i * 32768,
            bufs[(i + 1) & 1], out_pts, wc, wn, xyz, out, last);
    }
}